// Round 3
// baseline (73.003 us; speedup 1.0000x reference)
//
#include <hip/hip_runtime.h>
#include <hip/hip_bf16.h>

// Additive attention weights: B=2,H=4,LQ=LKV=512,D=64, fp32 in/out.
//   tanh(x) = 1 - 2/(1+e^{2x});  softmax drops uniform shift (sum w + b_logit)
//   => effective logit = sum_e (-2 w_e) * 1/(1 + exp2((qp+kp+b)*2*log2e))
// Kernel A precomputes qs=(qp+b_concat)*2log2e, ks=kp*2log2e into d_ws.

#define NQROWS 4096   // B*H*LQ

__device__ __forceinline__ float sig2(float x) {
  // 1 / (1 + exp2(x))
  const float u = __builtin_amdgcn_exp2f(x);
  return __builtin_amdgcn_rcpf(1.0f + u);
}

// async global->LDS, 16B per lane, wave-uniform LDS base + lane*16
#define GLL16(gp, lp)                                            \
  __builtin_amdgcn_global_load_lds(                              \
      (const __attribute__((address_space(1))) void*)(gp),       \
      (__attribute__((address_space(3))) void*)(lp), 16, 0, 0)

// ---------------- kernel A: projections ----------------
__global__ __launch_bounds__(256) void proj_kernel(
    const float* __restrict__ Q, const float* __restrict__ K,
    const float* __restrict__ W, const float* __restrict__ bC,
    float* __restrict__ qs, float* __restrict__ ks)
{
  const int t  = threadIdx.x;
  const int tr = t >> 6;        // 0..3
  const int e  = t & 63;
  const int rbase = blockIdx.x * 16;
  const bool isK = rbase >= NQROWS;
  const int r0 = isK ? rbase - NQROWS : rbase;
  const float* __restrict__ src = isK ? K : Q;
  const int off = isK ? 64 : 0;

  __shared__ float  srow[16][64];    // 4KB, broadcast reads
  __shared__ float4 wsh[64][16];     // 16KB, XOR-swizzled (f4 col ^ (row&7))

  for (int i = t; i < 16 * 64; i += 256)
    srow[i >> 6][i & 63] = src[(r0 + (i >> 6)) * 64 + (i & 63)];
  for (int i = t; i < 64 * 16; i += 256) {
    const int er = i >> 4, d4 = i & 15;
    wsh[er][d4 ^ (er & 7)] =
        reinterpret_cast<const float4*>(W + er * 128 + off)[d4];
  }
  __syncthreads();

  float acc0 = 0.f, acc1 = 0.f, acc2 = 0.f, acc3 = 0.f;
  const int rA = tr * 4;
  #pragma unroll
  for (int d4 = 0; d4 < 16; ++d4) {
    const float4 w4 = wsh[e][d4 ^ (e & 7)];
    const float4 s0 = *reinterpret_cast<const float4*>(&srow[rA + 0][d4 * 4]);
    const float4 s1 = *reinterpret_cast<const float4*>(&srow[rA + 1][d4 * 4]);
    const float4 s2 = *reinterpret_cast<const float4*>(&srow[rA + 2][d4 * 4]);
    const float4 s3 = *reinterpret_cast<const float4*>(&srow[rA + 3][d4 * 4]);
    acc0 = fmaf(s0.x, w4.x, acc0); acc0 = fmaf(s0.y, w4.y, acc0);
    acc0 = fmaf(s0.z, w4.z, acc0); acc0 = fmaf(s0.w, w4.w, acc0);
    acc1 = fmaf(s1.x, w4.x, acc1); acc1 = fmaf(s1.y, w4.y, acc1);
    acc1 = fmaf(s1.z, w4.z, acc1); acc1 = fmaf(s1.w, w4.w, acc1);
    acc2 = fmaf(s2.x, w4.x, acc2); acc2 = fmaf(s2.y, w4.y, acc2);
    acc2 = fmaf(s2.z, w4.z, acc2); acc2 = fmaf(s2.w, w4.w, acc2);
    acc3 = fmaf(s3.x, w4.x, acc3); acc3 = fmaf(s3.y, w4.y, acc3);
    acc3 = fmaf(s3.z, w4.z, acc3); acc3 = fmaf(s3.w, w4.w, acc3);
  }

  const float C2 = 2.8853900817779268f;   // 2*log2(e)
  const float bias = isK ? 0.0f : bC[e];
  float* __restrict__ dst = isK ? ks : qs;
  dst[(r0 + rA + 0) * 64 + e] = (acc0 + bias) * C2;
  dst[(r0 + rA + 1) * 64 + e] = (acc1 + bias) * C2;
  dst[(r0 + rA + 2) * 64 + e] = (acc2 + bias) * C2;
  dst[(r0 + rA + 3) * 64 + e] = (acc3 + bias) * C2;
}

// ---------------- kernel B: fused logits + masked softmax ----------------
// Grid: 1024 blocks (bh 0..7 x qblk 0..127), 256 threads = 4 waves,
// 1 q-row per wave. K staged in 8 tiles of 64 rows, double-buffered
// 2x16KB LDS via global_load_lds (no reg round-trip -> no spill).
// Swizzle both-sides (G21): linear LDS dest, XOR'd global SOURCE addr,
// XOR'd read: kp4[bf][row][c'] holds K[row][c' ^ (row&7)].
__global__ __launch_bounds__(256) void attn_kernel(
    const float* __restrict__ qs, const float* __restrict__ ks,
    const float* __restrict__ wl, const int* __restrict__ mask,
    float* __restrict__ out)
{
  const int t   = threadIdx.x;
  const int w   = t >> 6;        // wave 0..3
  const int tk  = t & 63;
  const int blk = blockIdx.x;
  const int bh  = blk >> 7;      // 0..7
  const int qb  = blk & 127;     // 0..127
  const int b   = bh >> 2;       // H=4
  const int q   = qb * 4 + w;    // this wave's q row

  __shared__ float4 kp4[2][64][16];   // 32KB double-buffered
  __shared__ float  qsh[4][64];
  __shared__ float  w2s[64];

  if (t < 64) w2s[t] = -2.0f * wl[t];
  qsh[w][tk] = qs[(bh * 512 + q) * 64 + tk];

  const float* __restrict__ kbase = ks + bh * 512 * 64;

  // wave w stages rows [w*16, w*16+16) of the 64-row tile; 4 instrs/wave,
  // each instr = 4 rows (64 lanes x 16B). LDS dest linear, source XOR'd.
  #define STAGE(bf, tile)                                                 \
    _Pragma("unroll")                                                     \
    for (int it = 0; it < 4; ++it) {                                      \
      const int r0  = w * 16 + it * 4;                                    \
      const int row = r0 + (tk >> 4);                                     \
      const int c   = (tk & 15) ^ (row & 7);                              \
      GLL16(kbase + ((tile) * 64 + row) * 64 + c * 4, &kp4[bf][r0][0]);   \
    }

  float acc[8];
  #pragma unroll
  for (int j = 0; j < 8; ++j) acc[j] = 0.f;

  STAGE(0, 0);
  __syncthreads();   // drains vmcnt -> tile 0 resident

  #pragma unroll
  for (int tile = 0; tile < 8; ++tile) {
    const int bf = tile & 1;
    if (tile < 7) STAGE(bf ^ 1, tile + 1);   // in flight during compute
    float a = 0.f;
    #pragma unroll
    for (int e4 = 0; e4 < 16; ++e4) {
      const float4 qa = *reinterpret_cast<const float4*>(&qsh[w][e4 * 4]);
      const float4 w4 = *reinterpret_cast<const float4*>(&w2s[e4 * 4]);
      const float4 kv = kp4[bf][tk][e4 ^ (tk & 7)];
      a = fmaf(w4.x, sig2(qa.x + kv.x), a);
      a = fmaf(w4.y, sig2(qa.y + kv.y), a);
      a = fmaf(w4.z, sig2(qa.z + kv.z), a);
      a = fmaf(w4.w, sig2(qa.w + kv.w), a);
    }
    acc[tile] = a;
    __syncthreads();  // all waves done reading bf; prefetch drained
  }

  // ---- mask + softmax (one row per wave: full-wave shfl); k = j*64+tk ----
  const int* __restrict__ mrow = mask + (b * 512 + q) * 512;
  int mv[8];
  #pragma unroll
  for (int j = 0; j < 8; ++j) mv[j] = mrow[j * 64 + tk];
  int lo = 0;
  #pragma unroll
  for (int j = 0; j < 8; ++j) lo |= mv[j];
  const bool rowany = __any(lo != 0);
  const float NEG = -__builtin_inff();
  #pragma unroll
  for (int j = 0; j < 8; ++j)
    if (rowany && mv[j] == 0) acc[j] = NEG;

  float m = acc[0];
  #pragma unroll
  for (int j = 1; j < 8; ++j) m = fmaxf(m, acc[j]);
  #pragma unroll
  for (int s = 1; s < 64; s <<= 1) m = fmaxf(m, __shfl_xor(m, s));

  const float L2E = 1.4426950408889634f;
  const float c = m * L2E;
  float p[8];
  float sum = 0.f;
  #pragma unroll
  for (int j = 0; j < 8; ++j) {
    p[j] = __builtin_amdgcn_exp2f(fmaf(acc[j], L2E, -c));
    sum += p[j];
  }
  #pragma unroll
  for (int s = 1; s < 64; s <<= 1) sum += __shfl_xor(sum, s);
  const float inv = 1.0f / sum;

  float* __restrict__ o = out + (bh * 512 + q) * 512;
  #pragma unroll
  for (int j = 0; j < 8; ++j)
    o[j * 64 + tk] = p[j] * inv;
}

extern "C" void kernel_launch(void* const* d_in, const int* in_sizes, int n_in,
                              void* d_out, int out_size, void* d_ws, size_t ws_size,
                              hipStream_t stream) {
  const float* Q  = (const float*)d_in[0];
  const float* K  = (const float*)d_in[1];
  // d_in[2] = values : unused by the reference output
  const int*   M  = (const int*)d_in[3];
  const float* W  = (const float*)d_in[4];
  const float* bC = (const float*)d_in[5];
  const float* wl = (const float*)d_in[6];
  // d_in[7] = b_logit : uniform shift, cancels in softmax
  float* out = (float*)d_out;
  float* qs = (float*)d_ws;            // 4096*64 floats = 1MB
  float* ks = qs + NQROWS * 64;        // 1MB

  proj_kernel<<<512, 256, 0, stream>>>(Q, K, W, bC, qs, ks);
  attn_kernel<<<1024, 256, 0, stream>>>(qs, ks, wl, M, out);
}

// Round 4
// 31.143 us; speedup vs baseline: 2.3442x; 2.3442x over previous
//
#include <hip/hip_runtime.h>
#include <hip/hip_bf16.h>

// Additive attention weights: B=2,H=4,LQ=LKV=512,D=64, fp32 in/out.
//   tanh(x) = 1 - 2/(1+e^{2x});  softmax drops uniform shift (sum w + b_logit)
//   => logit ~ sum_e (-2 w_e) / (1 + e^{2x_e}),  x = qp+kp+b
//   e^{2x} = EQ*EK with EQ=2^{(qp+b)*2log2e}, EK=2^{kp*2log2e} (precomputed!)
// Kernel A: EQ row-major [row][e]; EK TRANSPOSED [bh][e][k] so kernel B's
// k-dimension reads are lane-coalesced float4. Kernel B: no LDS K tile, no
// barriers in the hot loop; per eval = fma + rcp + fma.

#define NQROWS 4096   // B*H*LQ

// ---------------- kernel A: projections + exp2 ----------------
__global__ __launch_bounds__(256) void proj_kernel(
    const float* __restrict__ Q, const float* __restrict__ K,
    const float* __restrict__ W, const float* __restrict__ bC,
    float* __restrict__ eq, float* __restrict__ ekt)
{
  const int t  = threadIdx.x;
  const int tr = t >> 6;        // 0..3
  const int e  = t & 63;
  const int rbase = blockIdx.x * 16;
  const bool isK = rbase >= NQROWS;
  const int r0 = isK ? rbase - NQROWS : rbase;
  const float* __restrict__ src = isK ? K : Q;
  const int off = isK ? 64 : 0;

  __shared__ float  srow[16][64];    // 4KB, broadcast reads
  __shared__ float4 wsh[64][16];     // 16KB, XOR-swizzled (f4 col ^ (row&7))

  for (int i = t; i < 16 * 64; i += 256)
    srow[i >> 6][i & 63] = src[(r0 + (i >> 6)) * 64 + (i & 63)];
  for (int i = t; i < 64 * 16; i += 256) {
    const int er = i >> 4, d4 = i & 15;
    wsh[er][d4 ^ (er & 7)] =
        reinterpret_cast<const float4*>(W + er * 128 + off)[d4];
  }
  __syncthreads();

  float acc0 = 0.f, acc1 = 0.f, acc2 = 0.f, acc3 = 0.f;
  const int rA = tr * 4;
  #pragma unroll
  for (int d4 = 0; d4 < 16; ++d4) {
    const float4 w4 = wsh[e][d4 ^ (e & 7)];
    const float4 s0 = *reinterpret_cast<const float4*>(&srow[rA + 0][d4 * 4]);
    const float4 s1 = *reinterpret_cast<const float4*>(&srow[rA + 1][d4 * 4]);
    const float4 s2 = *reinterpret_cast<const float4*>(&srow[rA + 2][d4 * 4]);
    const float4 s3 = *reinterpret_cast<const float4*>(&srow[rA + 3][d4 * 4]);
    acc0 = fmaf(s0.x, w4.x, acc0); acc0 = fmaf(s0.y, w4.y, acc0);
    acc0 = fmaf(s0.z, w4.z, acc0); acc0 = fmaf(s0.w, w4.w, acc0);
    acc1 = fmaf(s1.x, w4.x, acc1); acc1 = fmaf(s1.y, w4.y, acc1);
    acc1 = fmaf(s1.z, w4.z, acc1); acc1 = fmaf(s1.w, w4.w, acc1);
    acc2 = fmaf(s2.x, w4.x, acc2); acc2 = fmaf(s2.y, w4.y, acc2);
    acc2 = fmaf(s2.z, w4.z, acc2); acc2 = fmaf(s2.w, w4.w, acc2);
    acc3 = fmaf(s3.x, w4.x, acc3); acc3 = fmaf(s3.y, w4.y, acc3);
    acc3 = fmaf(s3.z, w4.z, acc3); acc3 = fmaf(s3.w, w4.w, acc3);
  }

  const float C2 = 2.8853900817779268f;   // 2*log2(e)
  if (!isK) {
    const float bias = bC[e];
    eq[(r0 + rA + 0) * 64 + e] = __builtin_amdgcn_exp2f((acc0 + bias) * C2);
    eq[(r0 + rA + 1) * 64 + e] = __builtin_amdgcn_exp2f((acc1 + bias) * C2);
    eq[(r0 + rA + 2) * 64 + e] = __builtin_amdgcn_exp2f((acc2 + bias) * C2);
    eq[(r0 + rA + 3) * 64 + e] = __builtin_amdgcn_exp2f((acc3 + bias) * C2);
  } else {
    const int bh = (r0 + rA) >> 9;        // 16-row block stays in one bh
    const int k0 = (r0 + rA) & 511;
    float* __restrict__ dst = ekt + bh * 64 * 512 + e * 512 + k0;
    dst[0] = __builtin_amdgcn_exp2f(acc0 * C2);
    dst[1] = __builtin_amdgcn_exp2f(acc1 * C2);
    dst[2] = __builtin_amdgcn_exp2f(acc2 * C2);
    dst[3] = __builtin_amdgcn_exp2f(acc3 * C2);
  }
}

// ---------------- kernel B: fused logits + masked softmax ----------------
// Grid: 1024 blocks (bh 0..7 x qb 0..127), 256 threads = 4 waves,
// 1 q-row per wave. EK read directly from L2-resident transposed slab,
// float4 over k (lane-coalesced). Thread tk owns k in {4tk..4tk+3} and
// {256+4tk..256+4tk+3}. No LDS K tile, no hot-loop barriers.
__global__ __launch_bounds__(256) void attn_kernel(
    const float* __restrict__ eq, const float* __restrict__ ekt,
    const float* __restrict__ wl, const int* __restrict__ mask,
    float* __restrict__ out)
{
  const int t  = threadIdx.x;
  const int w  = t >> 6;        // wave 0..3
  const int tk = t & 63;
  const int bh = blockIdx.x >> 7;
  const int qb = blockIdx.x & 127;
  const int b  = bh >> 2;       // H=4
  const int q  = qb * 4 + w;    // this wave's q row

  __shared__ float qsh[4][64];
  __shared__ float w2s[64];
  if (t < 64) w2s[t] = -2.0f * wl[t];
  qsh[w][tk] = eq[(bh * 512 + q) * 64 + tk];
  __syncthreads();

  const float4* __restrict__ kb4 =
      reinterpret_cast<const float4*>(ekt + bh * 64 * 512);

  float4 a0 = {0.f, 0.f, 0.f, 0.f};
  float4 a1 = {0.f, 0.f, 0.f, 0.f};

#define EVAL1(QE, WE, E)                                                      \
  {                                                                           \
    const float4 k0 = kb4[(E) * 128 + tk];                                    \
    const float4 k1 = kb4[(E) * 128 + 64 + tk];                               \
    a0.x = fmaf((WE), __builtin_amdgcn_rcpf(fmaf((QE), k0.x, 1.f)), a0.x);    \
    a0.y = fmaf((WE), __builtin_amdgcn_rcpf(fmaf((QE), k0.y, 1.f)), a0.y);    \
    a0.z = fmaf((WE), __builtin_amdgcn_rcpf(fmaf((QE), k0.z, 1.f)), a0.z);    \
    a0.w = fmaf((WE), __builtin_amdgcn_rcpf(fmaf((QE), k0.w, 1.f)), a0.w);    \
    a1.x = fmaf((WE), __builtin_amdgcn_rcpf(fmaf((QE), k1.x, 1.f)), a1.x);    \
    a1.y = fmaf((WE), __builtin_amdgcn_rcpf(fmaf((QE), k1.y, 1.f)), a1.y);    \
    a1.z = fmaf((WE), __builtin_amdgcn_rcpf(fmaf((QE), k1.z, 1.f)), a1.z);    \
    a1.w = fmaf((WE), __builtin_amdgcn_rcpf(fmaf((QE), k1.w, 1.f)), a1.w);    \
  }

  #pragma unroll 2
  for (int e4 = 0; e4 < 16; ++e4) {
    const float4 q4 = *reinterpret_cast<const float4*>(&qsh[w][e4 * 4]);
    const float4 w4 = *reinterpret_cast<const float4*>(&w2s[e4 * 4]);
    EVAL1(q4.x, w4.x, e4 * 4 + 0)
    EVAL1(q4.y, w4.y, e4 * 4 + 1)
    EVAL1(q4.z, w4.z, e4 * 4 + 2)
    EVAL1(q4.w, w4.w, e4 * 4 + 3)
  }

  // ---- mask + softmax (one row per wave: full-wave shfl) ----
  const int* __restrict__ mrow = mask + (b * 512 + q) * 512;
  const int4 m0 = *reinterpret_cast<const int4*>(mrow + 4 * tk);
  const int4 m1 = *reinterpret_cast<const int4*>(mrow + 256 + 4 * tk);
  const int lo = m0.x | m0.y | m0.z | m0.w | m1.x | m1.y | m1.z | m1.w;
  const bool rowany = __any(lo != 0);
  const float NEG = -__builtin_inff();
  if (rowany) {
    if (m0.x == 0) a0.x = NEG;
    if (m0.y == 0) a0.y = NEG;
    if (m0.z == 0) a0.z = NEG;
    if (m0.w == 0) a0.w = NEG;
    if (m1.x == 0) a1.x = NEG;
    if (m1.y == 0) a1.y = NEG;
    if (m1.z == 0) a1.z = NEG;
    if (m1.w == 0) a1.w = NEG;
  }

  float mm = fmaxf(fmaxf(fmaxf(a0.x, a0.y), fmaxf(a0.z, a0.w)),
                   fmaxf(fmaxf(a1.x, a1.y), fmaxf(a1.z, a1.w)));
  #pragma unroll
  for (int s = 1; s < 64; s <<= 1) mm = fmaxf(mm, __shfl_xor(mm, s));

  const float L2E = 1.4426950408889634f;
  const float c = mm * L2E;
  float p[8];
  p[0] = __builtin_amdgcn_exp2f(fmaf(a0.x, L2E, -c));
  p[1] = __builtin_amdgcn_exp2f(fmaf(a0.y, L2E, -c));
  p[2] = __builtin_amdgcn_exp2f(fmaf(a0.z, L2E, -c));
  p[3] = __builtin_amdgcn_exp2f(fmaf(a0.w, L2E, -c));
  p[4] = __builtin_amdgcn_exp2f(fmaf(a1.x, L2E, -c));
  p[5] = __builtin_amdgcn_exp2f(fmaf(a1.y, L2E, -c));
  p[6] = __builtin_amdgcn_exp2f(fmaf(a1.z, L2E, -c));
  p[7] = __builtin_amdgcn_exp2f(fmaf(a1.w, L2E, -c));
  float sum = 0.f;
  #pragma unroll
  for (int j = 0; j < 8; ++j) sum += p[j];
  #pragma unroll
  for (int s = 1; s < 64; s <<= 1) sum += __shfl_xor(sum, s);
  const float inv = 1.0f / sum;

  float* __restrict__ o = out + (bh * 512 + q) * 512;
  float4 o0 = {p[0] * inv, p[1] * inv, p[2] * inv, p[3] * inv};
  float4 o1 = {p[4] * inv, p[5] * inv, p[6] * inv, p[7] * inv};
  *reinterpret_cast<float4*>(o + 4 * tk) = o0;
  *reinterpret_cast<float4*>(o + 256 + 4 * tk) = o1;
}

extern "C" void kernel_launch(void* const* d_in, const int* in_sizes, int n_in,
                              void* d_out, int out_size, void* d_ws, size_t ws_size,
                              hipStream_t stream) {
  const float* Q  = (const float*)d_in[0];
  const float* K  = (const float*)d_in[1];
  // d_in[2] = values : unused by the reference output
  const int*   M  = (const int*)d_in[3];
  const float* W  = (const float*)d_in[4];
  const float* bC = (const float*)d_in[5];
  const float* wl = (const float*)d_in[6];
  // d_in[7] = b_logit : uniform shift, cancels in softmax
  float* out = (float*)d_out;
  float* eqbuf  = (float*)d_ws;            // 4096*64 floats = 1MB
  float* ektbuf = eqbuf + NQROWS * 64;     // 8*64*512 floats = 1MB, transposed

  proj_kernel<<<512, 256, 0, stream>>>(Q, K, W, bC, eqbuf, ektbuf);
  attn_kernel<<<1024, 256, 0, stream>>>(eqbuf, ektbuf, wl, M, out);
}

// Round 5
// 30.646 us; speedup vs baseline: 2.3821x; 1.0162x over previous
//
#include <hip/hip_runtime.h>
#include <hip/hip_bf16.h>

// Additive attention weights: B=2,H=4,LQ=LKV=512,D=64, fp32 in/out.
//   tanh(x) = 1 - 2/(1+e^{2x});  softmax drops uniform shift (sum w + b_logit)
//   => logit ~ sum_e w'_e/(1+e^{2x_e}),  w' = -2w,  x = qp+kp+b
//   e^{2x} = EQ*EK,  EQ=2^{(qp+b)*2log2e}, EK=2^{kp*2log2e}  (precomputed)
// 4-way rational combine (1 rcp per 4 e-terms):
//   sum_i w_i/t_i = [(w0 t1 + w1 t0) t2 t3 + (w2 t3 + w3 t2) t0 t1] / (t0 t1 t2 t3)
// Kernel A: EQ row-major [row][e]; EK TRANSPOSED [bh][e][k] (coalesced float4
// over k in kernel B). Kernel B: no LDS K tile; L2-resident slab; 8 waves =
// 4 q-rows x 2 k-halves per block for 32 waves/CU.

#define NQROWS 4096   // B*H*LQ

// ---------------- kernel A: projections + exp2 ----------------
__global__ __launch_bounds__(256) void proj_kernel(
    const float* __restrict__ Q, const float* __restrict__ K,
    const float* __restrict__ W, const float* __restrict__ bC,
    float* __restrict__ eq, float* __restrict__ ekt)
{
  const int t  = threadIdx.x;
  const int tr = t >> 6;        // 0..3
  const int e  = t & 63;
  const int rbase = blockIdx.x * 16;
  const bool isK = rbase >= NQROWS;
  const int r0 = isK ? rbase - NQROWS : rbase;
  const float* __restrict__ src = isK ? K : Q;
  const int off = isK ? 64 : 0;

  __shared__ float  srow[16][64];    // 4KB, broadcast reads
  __shared__ float4 wsh[64][16];     // 16KB, XOR-swizzled (f4 col ^ (row&7))

  for (int i = t; i < 16 * 64; i += 256)
    srow[i >> 6][i & 63] = src[(r0 + (i >> 6)) * 64 + (i & 63)];
  for (int i = t; i < 64 * 16; i += 256) {
    const int er = i >> 4, d4 = i & 15;
    wsh[er][d4 ^ (er & 7)] =
        reinterpret_cast<const float4*>(W + er * 128 + off)[d4];
  }
  __syncthreads();

  float acc0 = 0.f, acc1 = 0.f, acc2 = 0.f, acc3 = 0.f;
  const int rA = tr * 4;
  #pragma unroll
  for (int d4 = 0; d4 < 16; ++d4) {
    const float4 w4 = wsh[e][d4 ^ (e & 7)];
    const float4 s0 = *reinterpret_cast<const float4*>(&srow[rA + 0][d4 * 4]);
    const float4 s1 = *reinterpret_cast<const float4*>(&srow[rA + 1][d4 * 4]);
    const float4 s2 = *reinterpret_cast<const float4*>(&srow[rA + 2][d4 * 4]);
    const float4 s3 = *reinterpret_cast<const float4*>(&srow[rA + 3][d4 * 4]);
    acc0 = fmaf(s0.x, w4.x, acc0); acc0 = fmaf(s0.y, w4.y, acc0);
    acc0 = fmaf(s0.z, w4.z, acc0); acc0 = fmaf(s0.w, w4.w, acc0);
    acc1 = fmaf(s1.x, w4.x, acc1); acc1 = fmaf(s1.y, w4.y, acc1);
    acc1 = fmaf(s1.z, w4.z, acc1); acc1 = fmaf(s1.w, w4.w, acc1);
    acc2 = fmaf(s2.x, w4.x, acc2); acc2 = fmaf(s2.y, w4.y, acc2);
    acc2 = fmaf(s2.z, w4.z, acc2); acc2 = fmaf(s2.w, w4.w, acc2);
    acc3 = fmaf(s3.x, w4.x, acc3); acc3 = fmaf(s3.y, w4.y, acc3);
    acc3 = fmaf(s3.z, w4.z, acc3); acc3 = fmaf(s3.w, w4.w, acc3);
  }

  const float C2 = 2.8853900817779268f;   // 2*log2(e)
  if (!isK) {
    const float bias = bC[e];
    eq[(r0 + rA + 0) * 64 + e] = __builtin_amdgcn_exp2f((acc0 + bias) * C2);
    eq[(r0 + rA + 1) * 64 + e] = __builtin_amdgcn_exp2f((acc1 + bias) * C2);
    eq[(r0 + rA + 2) * 64 + e] = __builtin_amdgcn_exp2f((acc2 + bias) * C2);
    eq[(r0 + rA + 3) * 64 + e] = __builtin_amdgcn_exp2f((acc3 + bias) * C2);
  } else {
    const int bh = (r0 + rA) >> 9;        // 16-row block stays in one bh
    const int k0 = (r0 + rA) & 511;
    float* __restrict__ dst = ekt + bh * 64 * 512 + e * 512 + k0;
    dst[0] = __builtin_amdgcn_exp2f(acc0 * C2);
    dst[1] = __builtin_amdgcn_exp2f(acc1 * C2);
    dst[2] = __builtin_amdgcn_exp2f(acc2 * C2);
    dst[3] = __builtin_amdgcn_exp2f(acc3 * C2);
  }
}

// ---------------- kernel B: fused logits + masked softmax ----------------
// Grid: 1024 blocks (bh 0..7 x qb 0..127), 512 threads = 8 waves.
// Wave w: q-row rw=w>>1 (q=qb*4+rw), k-half h=w&1. Each thread owns the
// float4 of k at h*256 + 4*tk. 2-barrier cross-wave softmax combine.
__global__ __launch_bounds__(512) void attn_kernel(
    const float* __restrict__ eq, const float* __restrict__ ekt,
    const float* __restrict__ wl, const int* __restrict__ mask,
    float* __restrict__ out)
{
  const int t  = threadIdx.x;
  const int w  = t >> 6;        // wave 0..7
  const int tk = t & 63;
  const int rw = w >> 1;        // q-row in block 0..3
  const int h  = w & 1;         // k-half
  const int bh = blockIdx.x >> 7;
  const int qb = blockIdx.x & 127;
  const int b  = bh >> 2;       // H=4
  const int q  = qb * 4 + rw;

  __shared__ float qsh[4][64];
  __shared__ float w2s[64];
  __shared__ float s_any[8], s_mmax[8], s_rmax[8], s_sum[8];

  if (t < 64) w2s[t] = -2.0f * wl[t];
  if (h == 0) qsh[rw][tk] = eq[(bh * 512 + q) * 64 + tk];
  __syncthreads();

  // EK slab for this bh, float4 view; this thread's k-column
  const float4* __restrict__ kq =
      reinterpret_cast<const float4*>(ekt + bh * 64 * 512) + h * 64 + tk;

  float4 acc = {0.f, 0.f, 0.f, 0.f};

#define QUADC(C)                                                              \
  {                                                                           \
    const float t0 = fmaf(q4.x, K0.C, 1.f);                                   \
    const float t1 = fmaf(q4.y, K1.C, 1.f);                                   \
    const float t2 = fmaf(q4.z, K2.C, 1.f);                                   \
    const float t3 = fmaf(q4.w, K3.C, 1.f);                                   \
    const float t01 = t0 * t1, t23 = t2 * t3;                                 \
    const float den = t01 * t23;                                              \
    const float n01 = fmaf(w4.x, t1, w4.y * t0);                              \
    const float n23 = fmaf(w4.z, t3, w4.w * t2);                              \
    const float num = fmaf(n01, t23, n23 * t01);                              \
    acc.C = fmaf(num, __builtin_amdgcn_rcpf(den), acc.C);                     \
  }

  #pragma unroll 2
  for (int eb = 0; eb < 16; ++eb) {
    const float4 q4 = *reinterpret_cast<const float4*>(&qsh[rw][eb * 4]);
    const float4 w4 = *reinterpret_cast<const float4*>(&w2s[eb * 4]);
    const float4 K0 = kq[(eb * 4 + 0) * 128];
    const float4 K1 = kq[(eb * 4 + 1) * 128];
    const float4 K2 = kq[(eb * 4 + 2) * 128];
    const float4 K3 = kq[(eb * 4 + 3) * 128];
    QUADC(x) QUADC(y) QUADC(z) QUADC(w)
  }

  // ---- mask + split-row softmax ----
  const int* __restrict__ mrow = mask + (b * 512 + q) * 512 + h * 256;
  const int4 mv = *reinterpret_cast<const int4*>(mrow + 4 * tk);
  const int lo = mv.x | mv.y | mv.z | mv.w;
  const float hany = __any(lo != 0) ? 1.0f : 0.0f;

  const float NEG = -__builtin_inff();
  float4 am = acc;                      // masked copy (unconditional)
  if (mv.x == 0) am.x = NEG;
  if (mv.y == 0) am.y = NEG;
  if (mv.z == 0) am.z = NEG;
  if (mv.w == 0) am.w = NEG;

  float rmax = fmaxf(fmaxf(acc.x, acc.y), fmaxf(acc.z, acc.w));
  float mmax = fmaxf(fmaxf(am.x, am.y), fmaxf(am.z, am.w));
  #pragma unroll
  for (int s = 1; s < 64; s <<= 1) {
    rmax = fmaxf(rmax, __shfl_xor(rmax, s));
    mmax = fmaxf(mmax, __shfl_xor(mmax, s));
  }
  if (tk == 0) { s_any[w] = hany; s_mmax[w] = mmax; s_rmax[w] = rmax; }
  __syncthreads();

  const int wp = w & ~1;               // row's wave pair base
  const bool rowany = (s_any[wp] + s_any[wp + 1]) > 0.0f;
  const float m = rowany ? fmaxf(s_mmax[wp], s_mmax[wp + 1])
                         : fmaxf(s_rmax[wp], s_rmax[wp + 1]);
  const float4 av = rowany ? am : acc;

  const float L2E = 1.4426950408889634f;
  const float c = m * L2E;
  float4 p;
  p.x = __builtin_amdgcn_exp2f(fmaf(av.x, L2E, -c));
  p.y = __builtin_amdgcn_exp2f(fmaf(av.y, L2E, -c));
  p.z = __builtin_amdgcn_exp2f(fmaf(av.z, L2E, -c));
  p.w = __builtin_amdgcn_exp2f(fmaf(av.w, L2E, -c));
  float sum = p.x + p.y + p.z + p.w;
  #pragma unroll
  for (int s = 1; s < 64; s <<= 1) sum += __shfl_xor(sum, s);
  if (tk == 0) s_sum[w] = sum;
  __syncthreads();

  const float inv = 1.0f / (s_sum[wp] + s_sum[wp + 1]);
  float4 o4 = {p.x * inv, p.y * inv, p.z * inv, p.w * inv};
  float* __restrict__ o = out + (bh * 512 + q) * 512 + h * 256;
  *reinterpret_cast<float4*>(o + 4 * tk) = o4;
}

extern "C" void kernel_launch(void* const* d_in, const int* in_sizes, int n_in,
                              void* d_out, int out_size, void* d_ws, size_t ws_size,
                              hipStream_t stream) {
  const float* Q  = (const float*)d_in[0];
  const float* K  = (const float*)d_in[1];
  // d_in[2] = values : unused by the reference output
  const int*   M  = (const int*)d_in[3];
  const float* W  = (const float*)d_in[4];
  const float* bC = (const float*)d_in[5];
  const float* wl = (const float*)d_in[6];
  // d_in[7] = b_logit : uniform shift, cancels in softmax
  float* out = (float*)d_out;
  float* eqbuf  = (float*)d_ws;            // 4096*64 floats = 1MB
  float* ektbuf = eqbuf + NQROWS * 64;     // 8*64*512 floats = 1MB, transposed

  proj_kernel<<<512, 256, 0, stream>>>(Q, K, W, bC, eqbuf, ektbuf);
  attn_kernel<<<1024, 512, 0, stream>>>(eqbuf, ektbuf, wl, M, out);
}

// Round 6
// 29.720 us; speedup vs baseline: 2.4563x; 1.0311x over previous
//
#include <hip/hip_runtime.h>
#include <hip/hip_bf16.h>

// Additive attention weights: B=2,H=4,LQ=LKV=512,D=64, fp32 in/out.
//   tanh(x) = 1 - 2/(1+e^{2x});  softmax drops uniform shift (sum w + b_logit)
//   => logit ~ sum_e w'_e/(1+e^{2x_e}),  w' = -2w,  x = qp+kp+b
//   e^{2x} = EQ*EK,  EQ=2^{(qp+b)*2log2e}, EK=2^{kp*2log2e}  (precomputed)
// 4-way rational combine (1 rcp per 4 e-terms):
//   sum_i w_i/t_i = [(w0 t1 + w1 t0) t2 t3 + (w2 t3 + w3 t2) t0 t1]/(t0 t1 t2 t3)
// EK stored TRANSPOSED [bh][e][k] (coalesced float4-over-k reads in attn).
// attn: L2-direct (no LDS K tile), XCD-affine bh, reg-rotated prefetch,
// launch_bounds(512,8) to pin 8 waves/SIMD.

#define NQROWS 4096   // B*H*LQ

// ---------------- kernel A: projections + exp2 ----------------
// 8 rows/block: blocks [0,512) Q rows, [512,1024) K rows. 4 waves/block.
__global__ __launch_bounds__(256) void proj_kernel(
    const float* __restrict__ Q, const float* __restrict__ K,
    const float* __restrict__ W, const float* __restrict__ bC,
    float* __restrict__ eq, float* __restrict__ ekt)
{
  const int t  = threadIdx.x;
  const int tr = t >> 6;        // 0..3
  const int e  = t & 63;
  const int rbase = blockIdx.x * 8;
  const bool isK = rbase >= NQROWS;
  const int r0 = isK ? rbase - NQROWS : rbase;
  const float* __restrict__ src = isK ? K : Q;
  const int off = isK ? 64 : 0;

  __shared__ float  srow[8][64];     // 2KB
  __shared__ float4 wsh[64][16];     // 16KB, XOR-swizzled (f4 col ^ (row&7))
  __shared__ float  trsp[64][9];     // 2.3KB, K-store transpose (pad 9)

  for (int i = t; i < 8 * 64; i += 256)
    srow[i >> 6][i & 63] = src[(r0 + (i >> 6)) * 64 + (i & 63)];
  for (int i = t; i < 64 * 16; i += 256) {
    const int er = i >> 4, d4 = i & 15;
    wsh[er][d4 ^ (er & 7)] =
        reinterpret_cast<const float4*>(W + er * 128 + off)[d4];
  }
  __syncthreads();

  float acc0 = 0.f, acc1 = 0.f;
  const int rA = tr * 2;
  #pragma unroll
  for (int d4 = 0; d4 < 16; ++d4) {
    const float4 w4 = wsh[e][d4 ^ (e & 7)];
    const float4 s0 = *reinterpret_cast<const float4*>(&srow[rA + 0][d4 * 4]);
    const float4 s1 = *reinterpret_cast<const float4*>(&srow[rA + 1][d4 * 4]);
    acc0 = fmaf(s0.x, w4.x, acc0); acc0 = fmaf(s0.y, w4.y, acc0);
    acc0 = fmaf(s0.z, w4.z, acc0); acc0 = fmaf(s0.w, w4.w, acc0);
    acc1 = fmaf(s1.x, w4.x, acc1); acc1 = fmaf(s1.y, w4.y, acc1);
    acc1 = fmaf(s1.z, w4.z, acc1); acc1 = fmaf(s1.w, w4.w, acc1);
  }

  const float C2 = 2.8853900817779268f;   // 2*log2(e)
  if (!isK) {
    const float bias = bC[e];
    eq[(r0 + rA + 0) * 64 + e] = __builtin_amdgcn_exp2f((acc0 + bias) * C2);
    eq[(r0 + rA + 1) * 64 + e] = __builtin_amdgcn_exp2f((acc1 + bias) * C2);
  } else {
    // transpose in LDS, then coalesced store to ekt[bh][e][k0..k0+7]
    trsp[e][rA + 0] = __builtin_amdgcn_exp2f(acc0 * C2);
    trsp[e][rA + 1] = __builtin_amdgcn_exp2f(acc1 * C2);
    __syncthreads();                       // block-uniform branch: legal
    const int bh = r0 >> 9;
    const int k0 = r0 & 511;
    float* __restrict__ dst = ekt + bh * 64 * 512 + k0;
    #pragma unroll
    for (int iter = 0; iter < 2; ++iter) {
      const int i  = t + iter * 256;
      const int e2 = i >> 3, kk = i & 7;
      dst[e2 * 512 + kk] = trsp[e2][kk];
    }
  }
}

// ---------------- kernel B: fused logits + masked softmax ----------------
// Grid: 1024 blocks; bh = blk&7 (XCD-affine: each XCD's L2 keeps one
// 128KB EK slab), qb = blk>>3. 512 threads = 8 waves: wave w -> q-row
// rw=w>>1, k-half h=w&1; thread owns float4 of k at h*256+4*tk.
// Register-rotated prefetch (next e-block's 4 float4 in flight).
__global__ __launch_bounds__(512, 8) void attn_kernel(
    const float* __restrict__ eq, const float* __restrict__ ekt,
    const float* __restrict__ wl, const int* __restrict__ mask,
    float* __restrict__ out)
{
  const int t  = threadIdx.x;
  const int w  = t >> 6;        // wave 0..7
  const int tk = t & 63;
  const int rw = w >> 1;        // q-row in block 0..3
  const int h  = w & 1;         // k-half
  const int bh = blockIdx.x & 7;
  const int qb = blockIdx.x >> 3;
  const int b  = bh >> 2;       // H=4
  const int q  = qb * 4 + rw;

  __shared__ float qsh[4][64];
  __shared__ float w2s[64];
  __shared__ float s_any[8], s_mmax[8], s_rmax[8], s_sum[8];

  if (t < 64) w2s[t] = -2.0f * wl[t];
  if (h == 0) qsh[rw][tk] = eq[(bh * 512 + q) * 64 + tk];

  // early mask load: hide HBM/L3 latency under the main loop
  const int* __restrict__ mrow = mask + (b * 512 + q) * 512 + h * 256;
  const int4 mv = *reinterpret_cast<const int4*>(mrow + 4 * tk);

  __syncthreads();

  const float4* __restrict__ kq =
      reinterpret_cast<const float4*>(ekt + bh * 64 * 512) + h * 64 + tk;

  float4 acc = {0.f, 0.f, 0.f, 0.f};

#define QUADC(C)                                                              \
  {                                                                           \
    const float t0 = fmaf(q4.x, K0.C, 1.f);                                   \
    const float t1 = fmaf(q4.y, K1.C, 1.f);                                   \
    const float t2 = fmaf(q4.z, K2.C, 1.f);                                   \
    const float t3 = fmaf(q4.w, K3.C, 1.f);                                   \
    const float t01 = t0 * t1, t23 = t2 * t3;                                 \
    const float den = t01 * t23;                                              \
    const float n01 = fmaf(w4.x, t1, w4.y * t0);                              \
    const float n23 = fmaf(w4.z, t3, w4.w * t2);                              \
    const float num = fmaf(n01, t23, n23 * t01);                              \
    acc.C = fmaf(num, __builtin_amdgcn_rcpf(den), acc.C);                     \
  }

  float4 K0 = kq[0 * 128], K1 = kq[1 * 128], K2 = kq[2 * 128], K3 = kq[3 * 128];
  #pragma unroll
  for (int eb = 0; eb < 15; ++eb) {
    const float4 N0 = kq[(eb * 4 + 4) * 128];
    const float4 N1 = kq[(eb * 4 + 5) * 128];
    const float4 N2 = kq[(eb * 4 + 6) * 128];
    const float4 N3 = kq[(eb * 4 + 7) * 128];
    const float4 q4 = *reinterpret_cast<const float4*>(&qsh[rw][eb * 4]);
    const float4 w4 = *reinterpret_cast<const float4*>(&w2s[eb * 4]);
    QUADC(x) QUADC(y) QUADC(z) QUADC(w)
    K0 = N0; K1 = N1; K2 = N2; K3 = N3;
  }
  {
    const float4 q4 = *reinterpret_cast<const float4*>(&qsh[rw][60]);
    const float4 w4 = *reinterpret_cast<const float4*>(&w2s[60]);
    QUADC(x) QUADC(y) QUADC(z) QUADC(w)
  }

  // ---- mask + split-row softmax (2 waves per row) ----
  const int lo = mv.x | mv.y | mv.z | mv.w;
  const float hany = __any(lo != 0) ? 1.0f : 0.0f;

  const float NEG = -__builtin_inff();
  float4 am = acc;
  if (mv.x == 0) am.x = NEG;
  if (mv.y == 0) am.y = NEG;
  if (mv.z == 0) am.z = NEG;
  if (mv.w == 0) am.w = NEG;

  float rmax = fmaxf(fmaxf(acc.x, acc.y), fmaxf(acc.z, acc.w));
  float mmax = fmaxf(fmaxf(am.x, am.y), fmaxf(am.z, am.w));
  #pragma unroll
  for (int s = 1; s < 64; s <<= 1) {
    rmax = fmaxf(rmax, __shfl_xor(rmax, s));
    mmax = fmaxf(mmax, __shfl_xor(mmax, s));
  }
  if (tk == 0) { s_any[w] = hany; s_mmax[w] = mmax; s_rmax[w] = rmax; }
  __syncthreads();

  const int wp = w & ~1;               // row's wave-pair base
  const bool rowany = (s_any[wp] + s_any[wp + 1]) > 0.0f;
  const float m = rowany ? fmaxf(s_mmax[wp], s_mmax[wp + 1])
                         : fmaxf(s_rmax[wp], s_rmax[wp + 1]);
  const float4 av = rowany ? am : acc;

  const float L2E = 1.4426950408889634f;
  const float c = m * L2E;
  float4 p;
  p.x = __builtin_amdgcn_exp2f(fmaf(av.x, L2E, -c));
  p.y = __builtin_amdgcn_exp2f(fmaf(av.y, L2E, -c));
  p.z = __builtin_amdgcn_exp2f(fmaf(av.z, L2E, -c));
  p.w = __builtin_amdgcn_exp2f(fmaf(av.w, L2E, -c));
  float sum = p.x + p.y + p.z + p.w;
  #pragma unroll
  for (int s = 1; s < 64; s <<= 1) sum += __shfl_xor(sum, s);
  if (tk == 0) s_sum[w] = sum;
  __syncthreads();

  const float inv = 1.0f / (s_sum[wp] + s_sum[wp + 1]);
  float4 o4 = {p.x * inv, p.y * inv, p.z * inv, p.w * inv};
  float* __restrict__ o = out + (bh * 512 + q) * 512 + h * 256;
  *reinterpret_cast<float4*>(o + 4 * tk) = o4;
}

extern "C" void kernel_launch(void* const* d_in, const int* in_sizes, int n_in,
                              void* d_out, int out_size, void* d_ws, size_t ws_size,
                              hipStream_t stream) {
  const float* Q  = (const float*)d_in[0];
  const float* K  = (const float*)d_in[1];
  // d_in[2] = values : unused by the reference output
  const int*   M  = (const int*)d_in[3];
  const float* W  = (const float*)d_in[4];
  const float* bC = (const float*)d_in[5];
  const float* wl = (const float*)d_in[6];
  // d_in[7] = b_logit : uniform shift, cancels in softmax
  float* out = (float*)d_out;
  float* eqbuf  = (float*)d_ws;            // 4096*64 floats = 1MB
  float* ektbuf = eqbuf + NQROWS * 64;     // 8*64*512 floats = 1MB, transposed

  proj_kernel<<<1024, 256, 0, stream>>>(Q, K, W, bC, eqbuf, ektbuf);
  attn_kernel<<<1024, 512, 0, stream>>>(eqbuf, ektbuf, wl, M, out);
}